// Round 8
// baseline (223.705 us; speedup 1.0000x reference)
//
#include <hip/hip_runtime.h>
#include <hip/hip_bf16.h>

// MHA: B=2 S=2048 D=768 H=12 DK=64. fp32 in/out; bf16 MFMA internally.
#define B_  2
#define S_  2048
#define D_  768
#define H_  12
#define DK_ 64
#define NX_ (B_*S_*D_)      // 3145728 activation elements
#define NW_ (D_*D_)         // 589824 weight elements
#define CSC 0.18033688011112042f   // 0.125 * log2(e), baked into wq/bq

typedef __attribute__((ext_vector_type(8))) short  bf16x8;
typedef __attribute__((ext_vector_type(4))) float  f32x4;

__device__ __forceinline__ unsigned short f2bf(float f) {
    unsigned int u = __float_as_uint(f);
    u += 0x7fffu + ((u >> 16) & 1u);   // RNE
    return (unsigned short)(u >> 16);
}

// pack two fp32 -> two bf16 (+0x8000 then hi16) in 3 VALU ops
__device__ __forceinline__ unsigned pack_bf2(float a, float b) {
    const unsigned ua = __float_as_uint(a) + 0x8000u;
    const unsigned ub = __float_as_uint(b) + 0x8000u;
    return __builtin_amdgcn_perm(ub, ua, 0x07060302u);
}

__device__ __forceinline__ void async_cp16(const unsigned short* g,
                                           const unsigned short* lds_uniform_base) {
    __builtin_amdgcn_global_load_lds(
        (const __attribute__((address_space(1))) unsigned int*)(uintptr_t)g,
        (__attribute__((address_space(3))) unsigned int*)(unsigned int)(uintptr_t)lds_uniform_base,
        16, 0, 0);
}

// ---------------------------------------------------------------------------
// Fused fp32->bf16 cvt, xor-swizzled per 64-el k-block (group g8 -> g8^(n&7)).
// 1D grid, no dead blocks: 3*1536 activation blocks + 4*288 weight blocks.
// ---------------------------------------------------------------------------
struct CvtArgs { const float* s[7]; };

__global__ __launch_bounds__(256) void cvt_all(CvtArgs a,
                                               unsigned short* __restrict__ Xsw,
                                               unsigned short* __restrict__ Wsw) {
    const int bx = blockIdx.x;
    int y, inner;
    if (bx < 4608) { y = bx / 1536;       inner = bx % 1536; }
    else           { y = 3 + (bx - 4608) / 288; inner = (bx - 4608) % 288; }
    const int idx = inner * 256 + threadIdx.x;
    const int n = idx / 96;
    const int g = idx % 96;
    const float* src = a.s[y];
    const float zs = (y == 3) ? CSC : 1.0f;
    const float4 f0 = *(const float4*)(src + (long)n * D_ + g * 8);
    const float4 f1 = *(const float4*)(src + (long)n * D_ + g * 8 + 4);
    unsigned short o[8] = {f2bf(f0.x*zs), f2bf(f0.y*zs), f2bf(f0.z*zs), f2bf(f0.w*zs),
                           f2bf(f1.x*zs), f2bf(f1.y*zs), f2bf(f1.z*zs), f2bf(f1.w*zs)};
    const int kdst = (g >> 3) * 64 + (((g & 7) ^ (n & 7)) * 8);
    unsigned short* dst = (y >= 3) ? (Wsw + (long)(y - 3) * NW_) : (Xsw + (long)y * NX_);
    *(uint4*)(dst + (long)n * D_ + kdst) = *(const uint4*)o;
}

// ---------------------------------------------------------------------------
// Fused QKV projection. grid(32, 18): y -> zz = y/6, nb = y%6. Tile 128x128,
// BK=64, 4 waves 2x2. Both operands async-staged from swizzled bf16 global.
// Outputs: Q/K [bh][s][dk]; V transposed+pi-permuted [bh][dk][s'].
// ---------------------------------------------------------------------------
struct QkvArgs { const float* bias[3]; unsigned short* out[3]; };

__global__ __launch_bounds__(256, 2) void gemm_qkv(QkvArgs args,
                                                   const unsigned short* __restrict__ Xsw,
                                                   const unsigned short* __restrict__ Wsw) {
    __shared__ __align__(16) unsigned short smem[17408];
    unsigned short* As = smem;           // [128][64] swizzled
    unsigned short* Bs = smem + 8192;    // [128][64] swizzled

    const int t    = threadIdx.x;
    const int wave = t >> 6;
    const int lane = t & 63;
    const int l16  = lane & 15;
    const int quad = lane >> 4;
    const int wm   = wave >> 1, wn = wave & 1;
    const int m0   = blockIdx.x * 128;
    const int zz   = blockIdx.y / 6;
    const int nb   = blockIdx.y % 6;
    const int n0   = nb * 128;

    const unsigned short* Ap = Xsw + (long)zz * NX_;
    const unsigned short* Wp = Wsw + (long)zz * NW_;

    f32x4 acc[4][4];
#pragma unroll
    for (int s = 0; s < 4; s++)
#pragma unroll
        for (int j = 0; j < 4; j++) acc[s][j] = (f32x4){0.f, 0.f, 0.f, 0.f};

    const int lrow = lane >> 3;
    const int lcg  = lane & 7;

    for (int k0 = 0; k0 < D_; k0 += 64) {
        __syncthreads();
#pragma unroll
        for (int i = 0; i < 4; i++) {
            const int chunk = wave * 4 + i;
            async_cp16(Ap + (long)(m0 + chunk * 8 + lrow) * D_ + k0 + lcg * 8,
                       As + chunk * 512);
        }
#pragma unroll
        for (int i = 0; i < 4; i++) {
            const int chunk = wave * 4 + i;
            async_cp16(Wp + (long)(n0 + chunk * 8 + lrow) * D_ + k0 + lcg * 8,
                       Bs + chunk * 512);
        }
        __syncthreads();
#pragma unroll
        for (int ks = 0; ks < 2; ks++) {
            const int cg = ks * 4 + quad;
            bf16x8 af[4], bf[4];
#pragma unroll
            for (int s = 0; s < 4; s++) {
                const int r = wm * 64 + s * 16 + l16;
                af[s] = *(const bf16x8*)&As[r * 64 + ((cg ^ (r & 7)) * 8)];
            }
#pragma unroll
            for (int j = 0; j < 4; j++) {
                const int r = wn * 64 + j * 16 + l16;
                bf[j] = *(const bf16x8*)&Bs[r * 64 + ((cg ^ (r & 7)) * 8)];
            }
#pragma unroll
            for (int s = 0; s < 4; s++)
#pragma unroll
                for (int j = 0; j < 4; j++)
                    acc[s][j] = __builtin_amdgcn_mfma_f32_16x16x32_bf16(af[s], bf[j], acc[s][j], 0, 0, 0);
        }
    }
    __syncthreads();

    const int b     = m0 >> 11;
    const int sbase = m0 & (S_ - 1);
    const float zs  = (zz == 0) ? CSC : 1.0f;
    float bv[4];
#pragma unroll
    for (int j = 0; j < 4; j++) bv[j] = args.bias[zz][n0 + wn * 64 + j * 16 + l16] * zs;

    if (zz < 2) {
        unsigned short* Ls = smem;       // [128][136]
#pragma unroll
        for (int s = 0; s < 4; s++)
#pragma unroll
            for (int j = 0; j < 4; j++)
#pragma unroll
                for (int r = 0; r < 4; r++)
                    Ls[(wm * 64 + s * 16 + quad * 4 + r) * 136 + wn * 64 + j * 16 + l16] =
                        f2bf(acc[s][j][r] + bv[j]);
        __syncthreads();
        const int row  = t >> 1;
        const int half = t & 1;
        unsigned short* Op = args.out[zz];
#pragma unroll
        for (int i = 0; i < 8; i++) {
            const int col  = half * 64 + i * 8;
            const int head = nb * 2 + half;
            const uint4 v = *(const uint4*)&Ls[row * 136 + col];
            *(uint4*)(Op + ((long)(b * H_ + head) * S_ + sbase + row) * DK_ + (col & 63)) = v;
        }
    } else {
        unsigned short* Ls = smem;       // [2][64][136]
#pragma unroll
        for (int s = 0; s < 4; s++)
#pragma unroll
            for (int j = 0; j < 4; j++)
#pragma unroll
                for (int r = 0; r < 4; r++) {
                    const int dk  = j * 16 + l16;
                    const int pos = wm * 64 + (quad * 4 + r) * 4 + s;   // pi-permute
                    Ls[wn * 8704 + dk * 136 + pos] = f2bf(acc[s][j][r] + bv[j]);
                }
        __syncthreads();
        const int rowIdx = t >> 1;
        const int hh = rowIdx >> 6, dk = rowIdx & 63;
        const int half = t & 1;
        unsigned short* Op = args.out[2];
#pragma unroll
        for (int i = 0; i < 8; i++) {
            const int col = half * 64 + i * 8;
            const uint4 v = *(const uint4*)&Ls[hh * 8704 + dk * 136 + col];
            const int head = nb * 2 + hh;
            *(uint4*)(Op + ((long)(b * H_ + head) * DK_ + dk) * S_ + sbase + col) = v;
        }
    }
}

// ---------------------------------------------------------------------------
// Flash attention, 2-WAVE blocks (128 thr), 64-row q-tiles, 2 strips/wave.
// K/V B-fragments read once per wave, reused across both strips -> LDS
// traffic per block-iter 120->64 KB. grid (32,24)=768 = 3/CU. No-max softmax
// (scale baked), pi-permuted packed P, piV, dbuf K/V + reg prefetch,
// ONE barrier per KV tile. Direct swizzled bf16 output.
// ---------------------------------------------------------------------------
__global__ __launch_bounds__(128, 2) void attn_kernel(
    const unsigned short* __restrict__ Q, const unsigned short* __restrict__ K,
    const unsigned short* __restrict__ Vt, unsigned short* __restrict__ Ao)
{
    const int t    = threadIdx.x;
    const int wave = t >> 6;            // 0..1
    const int lane = t & 63;
    const int l16  = lane & 15;
    const int quad = lane >> 4;
    const int qtile = blockIdx.x;       // 32 tiles of 64 rows
    const int bh    = blockIdx.y;       // 24

    const unsigned short* Qp = Q  + (long)bh * S_ * DK_;
    const unsigned short* Kp = K  + (long)bh * S_ * DK_;
    const unsigned short* Vp = Vt + (long)bh * DK_ * S_;

    __shared__ __align__(16) unsigned short smem[23040];   // 45 KB
    // Ks[0]@0 Ks[1]@4608 Vs[0]@9216 Vs[1]@13824 Ps@18432 (all [64][72])
    unsigned short* Ps = smem + 18432;

    // persistent Q fragments: 2 strips x 2 ks
    bf16x8 qfrag[2][2];
#pragma unroll
    for (int st = 0; st < 2; st++) {
        const long qoff = (long)(qtile * 64 + wave * 32 + st * 16 + l16) * DK_ + quad * 8;
        qfrag[st][0] = *(const bf16x8*)(Qp + qoff);
        qfrag[st][1] = *(const bf16x8*)(Qp + qoff + 32);
    }

    // staging map: each thread owns row srow, 32-col half sc0 (4 uint4)
    const int srow = t >> 1;            // 0..63
    const int sc0  = (t & 1) * 32;
    uint4 kreg[4], vreg[4];
    {
        const unsigned short* gk = Kp + (long)srow * DK_ + sc0;
        const unsigned short* gv = Vp + (long)srow * S_ + sc0;
#pragma unroll
        for (int i = 0; i < 4; i++) { kreg[i] = *(const uint4*)(gk + i * 8);
                                      vreg[i] = *(const uint4*)(gv + i * 8); }
    }
#pragma unroll
    for (int i = 0; i < 4; i++) {
        *(uint4*)&smem[srow * 72 + sc0 + i * 8]        = kreg[i];
        *(uint4*)&smem[9216 + srow * 72 + sc0 + i * 8] = vreg[i];
    }

    f32x4 oacc[2][4];
#pragma unroll
    for (int st = 0; st < 2; st++)
#pragma unroll
        for (int j = 0; j < 4; j++) oacc[st][j] = (f32x4){0.f, 0.f, 0.f, 0.f};
    float lsum[2][4] = {{0.f,0.f,0.f,0.f},{0.f,0.f,0.f,0.f}};

    for (int it = 0; it < 32; ++it) {
        const int co = (it & 1) * 4608;
        const int no = ((it & 1) ^ 1) * 4608;
        __syncthreads();                 // prev-iter commits visible
        const unsigned short* Ks = smem + co;
        const unsigned short* Vs = smem + 9216 + co;

        if (it < 31) {                   // prefetch next K/V tile into regs
            const int kv0 = (it + 1) * 64;
            const unsigned short* gk = Kp + (long)(kv0 + srow) * DK_ + sc0;
            const unsigned short* gv = Vp + (long)srow * S_ + kv0 + sc0;
#pragma unroll
            for (int i = 0; i < 4; i++) { kreg[i] = *(const uint4*)(gk + i * 8);
                                          vreg[i] = *(const uint4*)(gv + i * 8); }
        }

        // S = Q K^T : B-frag read once, used by both strips
        f32x4 sacc[2][4];
#pragma unroll
        for (int st = 0; st < 2; st++)
#pragma unroll
            for (int j = 0; j < 4; j++) sacc[st][j] = (f32x4){0.f, 0.f, 0.f, 0.f};
#pragma unroll
        for (int ks = 0; ks < 2; ks++)
#pragma unroll
            for (int j = 0; j < 4; j++) {
                const bf16x8 bf = *(const bf16x8*)&Ks[(j * 16 + l16) * 72 + ks * 32 + quad * 8];
#pragma unroll
                for (int st = 0; st < 2; st++)
                    sacc[st][j] = __builtin_amdgcn_mfma_f32_16x16x32_bf16(qfrag[st][ks], bf, sacc[st][j], 0, 0, 0);
            }

        // p = exp2(s); packed b64 P-stores, pi-permuted columns
#pragma unroll
        for (int st = 0; st < 2; st++)
#pragma unroll
            for (int r = 0; r < 4; r++) {
                const float p0 = exp2f(sacc[st][0][r]);
                const float p1 = exp2f(sacc[st][1][r]);
                const float p2 = exp2f(sacc[st][2][r]);
                const float p3 = exp2f(sacc[st][3][r]);
                lsum[st][r] += (p0 + p1) + (p2 + p3);
                uint2 pk = {pack_bf2(p0, p1), pack_bf2(p2, p3)};
                *(uint2*)&Ps[(wave * 32 + st * 16 + quad * 4 + r) * 72 + l16 * 4] = pk;
            }

        // O += P V : V-frag read once, both strips (wave-local P, no barrier)
#pragma unroll
        for (int ks = 0; ks < 2; ks++) {
            bf16x8 pf[2];
#pragma unroll
            for (int st = 0; st < 2; st++)
                pf[st] = *(const bf16x8*)&Ps[(wave * 32 + st * 16 + l16) * 72 + ks * 32 + quad * 8];
#pragma unroll
            for (int j = 0; j < 4; j++) {
                const bf16x8 vf = *(const bf16x8*)&Vs[(j * 16 + l16) * 72 + ks * 32 + quad * 8];
#pragma unroll
                for (int st = 0; st < 2; st++)
                    oacc[st][j] = __builtin_amdgcn_mfma_f32_16x16x32_bf16(pf[st], vf, oacc[st][j], 0, 0, 0);
            }
        }

        if (it < 31) {                   // commit prefetch to other buffer
#pragma unroll
            for (int i = 0; i < 4; i++) {
                *(uint4*)&smem[no + srow * 72 + sc0 + i * 8]        = kreg[i];
                *(uint4*)&smem[9216 + no + srow * 72 + sc0 + i * 8] = vreg[i];
            }
        }
    }

#pragma unroll
    for (int st = 0; st < 2; st++)
#pragma unroll
        for (int r = 0; r < 4; r++) {
#pragma unroll
            for (int off = 1; off < 16; off <<= 1)
                lsum[st][r] += __shfl_xor(lsum[st][r], off, 64);
            lsum[st][r] = 1.f / lsum[st][r];
        }

    // epilogue: bf16 via Ps (wave-local rows), b128 swizzled stores
    __syncthreads();
#pragma unroll
    for (int st = 0; st < 2; st++)
#pragma unroll
        for (int j = 0; j < 4; j++)
#pragma unroll
            for (int r = 0; r < 4; r++)
                Ps[(wave * 32 + st * 16 + quad * 4 + r) * 72 + j * 16 + l16] =
                    f2bf(oacc[st][j][r] * lsum[st][r]);
    __syncthreads();

    const int b = bh / H_, h = bh % H_;
    const int row = t >> 1;             // 0..63 (wave-local rows)
    const int c0  = (t & 1) * 32;
    const int qrow = qtile * 64 + row;
    const int key  = qrow & 7;
    unsigned short* dst = Ao + (long)(b * S_ + qrow) * D_ + h * DK_;
#pragma unroll
    for (int i = 0; i < 4; i++) {
        const int g8 = (c0 >> 3) + i;
        const uint4 v = *(const uint4*)&Ps[row * 72 + c0 + i * 8];
        *(uint4*)(dst + ((g8 ^ key) * 8)) = v;
    }
}

// ---------------------------------------------------------------------------
// Output projection: Ao_sw bf16 @ Wo_sw -> fp32 d_out + bias. Tile 64x64,
// grid (64,12)=768 blocks = 3/CU balanced. 4 waves 2x2 (wave 32x32), both
// operands async-staged. Single-pass LDS fp32 epilogue, dwordx4 stores.
// ---------------------------------------------------------------------------
__global__ __launch_bounds__(256, 2) void gemm_out(
    const unsigned short* __restrict__ A, const unsigned short* __restrict__ Wsw,
    const float* __restrict__ bias, float* __restrict__ Out)
{
    __shared__ __align__(16) unsigned short smem[8704];
    unsigned short* As = smem;           // [64][64] swizzled
    unsigned short* Bs = smem + 4096;    // [64][64] swizzled

    const int t    = threadIdx.x;
    const int wave = t >> 6;
    const int lane = t & 63;
    const int l16  = lane & 15;
    const int quad = lane >> 4;
    const int wm   = wave >> 1, wn = wave & 1;
    const int m0   = blockIdx.x * 64;
    const int n0   = blockIdx.y * 64;

    f32x4 acc[2][2];
#pragma unroll
    for (int s = 0; s < 2; s++)
#pragma unroll
        for (int j = 0; j < 2; j++) acc[s][j] = (f32x4){0.f, 0.f, 0.f, 0.f};

    const int lrow = lane >> 3;
    const int lcg  = lane & 7;

    for (int k0 = 0; k0 < D_; k0 += 64) {
        __syncthreads();
#pragma unroll
        for (int i = 0; i < 2; i++) {    // A: 8 chunks, 2 per wave
            const int chunk = wave * 2 + i;
            async_cp16(A + (long)(m0 + chunk * 8 + lrow) * D_ + k0 + lcg * 8,
                       As + chunk * 512);
        }
#pragma unroll
        for (int i = 0; i < 2; i++) {    // B: 8 chunks, 2 per wave
            const int chunk = wave * 2 + i;
            async_cp16(Wsw + (long)(n0 + chunk * 8 + lrow) * D_ + k0 + lcg * 8,
                       Bs + chunk * 512);
        }
        __syncthreads();
#pragma unroll
        for (int ks = 0; ks < 2; ks++) {
            const int cg = ks * 4 + quad;
            bf16x8 af[2], bf[2];
#pragma unroll
            for (int s = 0; s < 2; s++) {
                const int r = wm * 32 + s * 16 + l16;
                af[s] = *(const bf16x8*)&As[r * 64 + ((cg ^ (r & 7)) * 8)];
            }
#pragma unroll
            for (int j = 0; j < 2; j++) {
                const int r = wn * 32 + j * 16 + l16;
                bf[j] = *(const bf16x8*)&Bs[r * 64 + ((cg ^ (r & 7)) * 8)];
            }
#pragma unroll
            for (int s = 0; s < 2; s++)
#pragma unroll
                for (int j = 0; j < 2; j++)
                    acc[s][j] = __builtin_amdgcn_mfma_f32_16x16x32_bf16(af[s], bf[j], acc[s][j], 0, 0, 0);
        }
    }

    float bv[2];
#pragma unroll
    for (int j = 0; j < 2; j++) bv[j] = bias[n0 + wn * 32 + j * 16 + l16];

    __syncthreads();                     // done with As/Bs before reuse
    float* fl = (float*)smem;            // [64][67] = 17152 B <= 17408
#pragma unroll
    for (int s = 0; s < 2; s++)
#pragma unroll
        for (int j = 0; j < 2; j++)
#pragma unroll
            for (int r = 0; r < 4; r++)
                fl[(wm * 32 + s * 16 + quad * 4 + r) * 67 + wn * 32 + j * 16 + l16] =
                    acc[s][j][r] + bv[j];
    __syncthreads();
    const int row = t >> 2, c0 = (t & 3) * 16;
#pragma unroll
    for (int i = 0; i < 4; i++) {
        const float4 v = *(const float4*)&fl[row * 67 + c0 + i * 4];
        *(float4*)(Out + (long)(m0 + row) * D_ + n0 + c0 + i * 4) = v;
    }
}

extern "C" void kernel_launch(void* const* d_in, const int* in_sizes, int n_in,
                              void* d_out, int out_size, void* d_ws, size_t ws_size,
                              hipStream_t stream) {
    const float* k_in = (const float*)d_in[0];
    const float* q_in = (const float*)d_in[1];
    const float* v_in = (const float*)d_in[2];
    // d_in[3] = mask: no-op per reference
    const float* wq = (const float*)d_in[4];
    const float* bq = (const float*)d_in[5];
    const float* wk = (const float*)d_in[6];
    const float* bk = (const float*)d_in[7];
    const float* wv = (const float*)d_in[8];
    const float* bv = (const float*)d_in[9];
    const float* wo = (const float*)d_in[10];
    const float* bo = (const float*)d_in[11];

    unsigned short* ws = (unsigned short*)d_ws;
    unsigned short* Wsw = ws;                          // 4*NW bf16 swizzled
    unsigned short* Qb  = Wsw + 4ll * NW_;             // NX bf16
    unsigned short* Kb  = Qb + (long)NX_;
    unsigned short* Vt  = Kb + (long)NX_;
    unsigned short* Xsw = Vt + (long)NX_;              // 3*NX (dead after qkv)
    unsigned short* Ao  = Xsw;                         // aliases Xsw

    CvtArgs ca;
    ca.s[0] = q_in; ca.s[1] = k_in; ca.s[2] = v_in;
    ca.s[3] = wq;   ca.s[4] = wk;   ca.s[5] = wv;  ca.s[6] = wo;
    cvt_all<<<dim3(5760), 256, 0, stream>>>(ca, Xsw, Wsw);

    QkvArgs qa;
    qa.bias[0] = bq; qa.bias[1] = bk; qa.bias[2] = bv;
    qa.out[0] = Qb;  qa.out[1] = Kb;  qa.out[2] = Vt;
    gemm_qkv<<<dim3(32, 18), 256, 0, stream>>>(qa, Xsw, Wsw);

    attn_kernel<<<dim3(S_ / 64, B_ * H_), 128, 0, stream>>>(Qb, Kb, Vt, Ao);

    gemm_out<<<dim3(64, 12), 256, 0, stream>>>(Ao, Wsw + 3ll * NW_, bo, (float*)d_out);
}

// Round 9
// 214.639 us; speedup vs baseline: 1.0422x; 1.0422x over previous
//
#include <hip/hip_runtime.h>
#include <hip/hip_bf16.h>

// MHA: B=2 S=2048 D=768 H=12 DK=64. fp32 in/out; bf16 MFMA internally.
#define B_  2
#define S_  2048
#define D_  768
#define H_  12
#define DK_ 64
#define NX_ (B_*S_*D_)      // 3145728 activation elements
#define NW_ (D_*D_)         // 589824 weight elements
#define CSC 0.18033688011112042f   // 0.125 * log2(e), baked into wq/bq

typedef __attribute__((ext_vector_type(8))) short  bf16x8;
typedef __attribute__((ext_vector_type(4))) float  f32x4;

__device__ __forceinline__ unsigned short f2bf(float f) {
    unsigned int u = __float_as_uint(f);
    u += 0x7fffu + ((u >> 16) & 1u);   // RNE
    return (unsigned short)(u >> 16);
}

// pack two fp32 -> two bf16 (+0x8000 then hi16) in 3 VALU ops
__device__ __forceinline__ unsigned pack_bf2(float a, float b) {
    const unsigned ua = __float_as_uint(a) + 0x8000u;
    const unsigned ub = __float_as_uint(b) + 0x8000u;
    return __builtin_amdgcn_perm(ub, ua, 0x07060302u);
}

__device__ __forceinline__ void async_cp16(const unsigned short* g,
                                           const unsigned short* lds_uniform_base) {
    __builtin_amdgcn_global_load_lds(
        (const __attribute__((address_space(1))) unsigned int*)(uintptr_t)g,
        (__attribute__((address_space(3))) unsigned int*)(unsigned int)(uintptr_t)lds_uniform_base,
        16, 0, 0);
}

// ---------------------------------------------------------------------------
// Fused fp32->bf16 cvt, xor-swizzled per 64-el k-block (group g8 -> g8^(n&7)).
// 1D grid, no dead blocks: 3*1536 activation blocks + 4*288 weight blocks.
// ---------------------------------------------------------------------------
struct CvtArgs { const float* s[7]; };

__global__ __launch_bounds__(256) void cvt_all(CvtArgs a,
                                               unsigned short* __restrict__ Xsw,
                                               unsigned short* __restrict__ Wsw) {
    const int bx = blockIdx.x;
    int y, inner;
    if (bx < 4608) { y = bx / 1536;       inner = bx % 1536; }
    else           { y = 3 + (bx - 4608) / 288; inner = (bx - 4608) % 288; }
    const int idx = inner * 256 + threadIdx.x;
    const int n = idx / 96;
    const int g = idx % 96;
    const float* src = a.s[y];
    const float zs = (y == 3) ? CSC : 1.0f;
    const float4 f0 = *(const float4*)(src + (long)n * D_ + g * 8);
    const float4 f1 = *(const float4*)(src + (long)n * D_ + g * 8 + 4);
    unsigned short o[8] = {f2bf(f0.x*zs), f2bf(f0.y*zs), f2bf(f0.z*zs), f2bf(f0.w*zs),
                           f2bf(f1.x*zs), f2bf(f1.y*zs), f2bf(f1.z*zs), f2bf(f1.w*zs)};
    const int kdst = (g >> 3) * 64 + (((g & 7) ^ (n & 7)) * 8);
    unsigned short* dst = (y >= 3) ? (Wsw + (long)(y - 3) * NW_) : (Xsw + (long)y * NX_);
    *(uint4*)(dst + (long)n * D_ + kdst) = *(const uint4*)o;
}

// ---------------------------------------------------------------------------
// Fused QKV projection. grid(32, 18): y -> zz = y/6, nb = y%6. Tile 128x128,
// BK=64, 4 waves 2x2. Both operands async-staged from swizzled bf16 global.
// launch_bounds(256,3): all 576 blocks resident at once (no tail round).
// Outputs: Q/K [bh][s][dk]; V transposed+pi-permuted [bh][dk][s'].
// ---------------------------------------------------------------------------
struct QkvArgs { const float* bias[3]; unsigned short* out[3]; };

__global__ __launch_bounds__(256, 3) void gemm_qkv(QkvArgs args,
                                                   const unsigned short* __restrict__ Xsw,
                                                   const unsigned short* __restrict__ Wsw) {
    __shared__ __align__(16) unsigned short smem[17408];
    unsigned short* As = smem;           // [128][64] swizzled
    unsigned short* Bs = smem + 8192;    // [128][64] swizzled

    const int t    = threadIdx.x;
    const int wave = t >> 6;
    const int lane = t & 63;
    const int l16  = lane & 15;
    const int quad = lane >> 4;
    const int wm   = wave >> 1, wn = wave & 1;
    const int m0   = blockIdx.x * 128;
    const int zz   = blockIdx.y / 6;
    const int nb   = blockIdx.y % 6;
    const int n0   = nb * 128;

    const unsigned short* Ap = Xsw + (long)zz * NX_;
    const unsigned short* Wp = Wsw + (long)zz * NW_;

    f32x4 acc[4][4];
#pragma unroll
    for (int s = 0; s < 4; s++)
#pragma unroll
        for (int j = 0; j < 4; j++) acc[s][j] = (f32x4){0.f, 0.f, 0.f, 0.f};

    const int lrow = lane >> 3;
    const int lcg  = lane & 7;

    for (int k0 = 0; k0 < D_; k0 += 64) {
        __syncthreads();
#pragma unroll
        for (int i = 0; i < 4; i++) {
            const int chunk = wave * 4 + i;
            async_cp16(Ap + (long)(m0 + chunk * 8 + lrow) * D_ + k0 + lcg * 8,
                       As + chunk * 512);
        }
#pragma unroll
        for (int i = 0; i < 4; i++) {
            const int chunk = wave * 4 + i;
            async_cp16(Wp + (long)(n0 + chunk * 8 + lrow) * D_ + k0 + lcg * 8,
                       Bs + chunk * 512);
        }
        __syncthreads();
#pragma unroll
        for (int ks = 0; ks < 2; ks++) {
            const int cg = ks * 4 + quad;
            bf16x8 af[4], bf[4];
#pragma unroll
            for (int s = 0; s < 4; s++) {
                const int r = wm * 64 + s * 16 + l16;
                af[s] = *(const bf16x8*)&As[r * 64 + ((cg ^ (r & 7)) * 8)];
            }
#pragma unroll
            for (int j = 0; j < 4; j++) {
                const int r = wn * 64 + j * 16 + l16;
                bf[j] = *(const bf16x8*)&Bs[r * 64 + ((cg ^ (r & 7)) * 8)];
            }
#pragma unroll
            for (int s = 0; s < 4; s++)
#pragma unroll
                for (int j = 0; j < 4; j++)
                    acc[s][j] = __builtin_amdgcn_mfma_f32_16x16x32_bf16(af[s], bf[j], acc[s][j], 0, 0, 0);
        }
    }
    __syncthreads();

    const int b     = m0 >> 11;
    const int sbase = m0 & (S_ - 1);
    const float zs  = (zz == 0) ? CSC : 1.0f;
    float bv[4];
#pragma unroll
    for (int j = 0; j < 4; j++) bv[j] = args.bias[zz][n0 + wn * 64 + j * 16 + l16] * zs;

    if (zz < 2) {
        unsigned short* Ls = smem;       // [128][136]
#pragma unroll
        for (int s = 0; s < 4; s++)
#pragma unroll
            for (int j = 0; j < 4; j++)
#pragma unroll
                for (int r = 0; r < 4; r++)
                    Ls[(wm * 64 + s * 16 + quad * 4 + r) * 136 + wn * 64 + j * 16 + l16] =
                        f2bf(acc[s][j][r] + bv[j]);
        __syncthreads();
        const int row  = t >> 1;
        const int half = t & 1;
        unsigned short* Op = args.out[zz];
#pragma unroll
        for (int i = 0; i < 8; i++) {
            const int col  = half * 64 + i * 8;
            const int head = nb * 2 + half;
            const uint4 v = *(const uint4*)&Ls[row * 136 + col];
            *(uint4*)(Op + ((long)(b * H_ + head) * S_ + sbase + row) * DK_ + (col & 63)) = v;
        }
    } else {
        unsigned short* Ls = smem;       // [2][64][136]
#pragma unroll
        for (int s = 0; s < 4; s++)
#pragma unroll
            for (int j = 0; j < 4; j++)
#pragma unroll
                for (int r = 0; r < 4; r++) {
                    const int dk  = j * 16 + l16;
                    const int pos = wm * 64 + (quad * 4 + r) * 4 + s;   // pi-permute
                    Ls[wn * 8704 + dk * 136 + pos] = f2bf(acc[s][j][r] + bv[j]);
                }
        __syncthreads();
        const int rowIdx = t >> 1;
        const int hh = rowIdx >> 6, dk = rowIdx & 63;
        const int half = t & 1;
        unsigned short* Op = args.out[2];
#pragma unroll
        for (int i = 0; i < 8; i++) {
            const int col = half * 64 + i * 8;
            const uint4 v = *(const uint4*)&Ls[hh * 8704 + dk * 136 + col];
            const int head = nb * 2 + hh;
            *(uint4*)(Op + ((long)(b * H_ + head) * DK_ + dk) * S_ + sbase + col) = v;
        }
    }
}

// ---------------------------------------------------------------------------
// Flash attention (R7 structure), manually 2x-unrolled so double-buffer LDS
// offsets are compile-time immediates (cuts VALU addr arithmetic). 64-row
// q-tiles, 4 waves, grid (32,24)=768 = 3/CU, 12 waves/CU. No-max softmax
// (scale baked into Q), pi-permuted packed P, piV, dbuf K/V + reg prefetch,
// ONE barrier per KV tile. Direct swizzled bf16 output.
// ---------------------------------------------------------------------------
__global__ __launch_bounds__(256, 3) void attn_kernel(
    const unsigned short* __restrict__ Q, const unsigned short* __restrict__ K,
    const unsigned short* __restrict__ Vt, unsigned short* __restrict__ Ao)
{
    const int t    = threadIdx.x;
    const int wave = t >> 6;
    const int lane = t & 63;
    const int l16  = lane & 15;
    const int quad = lane >> 4;
    const int qtile = blockIdx.x;       // 32 tiles of 64 rows
    const int bh    = blockIdx.y;       // 24

    const unsigned short* Qp = Q  + (long)bh * S_ * DK_;
    const unsigned short* Kp = K  + (long)bh * S_ * DK_;
    const unsigned short* Vp = Vt + (long)bh * DK_ * S_;

    __shared__ __align__(16) unsigned short smem[23040];   // 45 KB
    // Ks0@0  Ks1@4608  Vs0@9216  Vs1@13824  Ps@18432  (each [64][72])
    unsigned short* Ps = smem + 18432;

    bf16x8 qfrag[2];
    {
        const long qoff = (long)(qtile * 64 + wave * 16 + l16) * DK_ + quad * 8;
        qfrag[0] = *(const bf16x8*)(Qp + qoff);
        qfrag[1] = *(const bf16x8*)(Qp + qoff + 32);
    }

    const int srow = t >> 2;            // 0..63
    const int scg  = (t & 3) * 16;
    uint4 kreg[2], vreg[2];
    // tile 0 -> buffer 0
    {
        const unsigned short* gk0 = Kp + (long)srow * DK_ + scg;
        const unsigned short* gv0 = Vp + (long)srow * S_ + scg;
        kreg[0] = *(const uint4*)gk0;  kreg[1] = *(const uint4*)(gk0 + 8);
        vreg[0] = *(const uint4*)gv0;  vreg[1] = *(const uint4*)(gv0 + 8);
    }
    *(uint4*)&smem[srow * 72 + scg]            = kreg[0];
    *(uint4*)&smem[srow * 72 + scg + 8]        = kreg[1];
    *(uint4*)&smem[9216 + srow * 72 + scg]     = vreg[0];
    *(uint4*)&smem[9216 + srow * 72 + scg + 8] = vreg[1];

    // rolling prefetch pointers (advance by constant stride each step)
    const unsigned short* gk = Kp + (long)(64 + srow) * DK_ + scg;
    const unsigned short* gv = Vp + (long)srow * S_ + 64 + scg;

    f32x4 oacc[4];
#pragma unroll
    for (int j = 0; j < 4; j++) oacc[j] = (f32x4){0.f, 0.f, 0.f, 0.f};
    float lsum[4] = {0.f, 0.f, 0.f, 0.f};

#define ATTN_STEP(CO, NO, PF)                                                  \
    {                                                                          \
        __syncthreads();                                                       \
        if (PF) {                                                              \
            kreg[0] = *(const uint4*)gk;  kreg[1] = *(const uint4*)(gk + 8);   \
            vreg[0] = *(const uint4*)gv;  vreg[1] = *(const uint4*)(gv + 8);   \
            gk += 64 * DK_;  gv += 64;                                         \
        }                                                                      \
        f32x4 sacc[4];                                                         \
        _Pragma("unroll")                                                      \
        for (int j = 0; j < 4; j++) sacc[j] = (f32x4){0.f, 0.f, 0.f, 0.f};     \
        _Pragma("unroll")                                                      \
        for (int ks = 0; ks < 2; ks++)                                         \
            _Pragma("unroll")                                                  \
            for (int j = 0; j < 4; j++) {                                      \
                const bf16x8 bf = *(const bf16x8*)&smem[(CO) +                 \
                    (j * 16 + l16) * 72 + ks * 32 + quad * 8];                 \
                sacc[j] = __builtin_amdgcn_mfma_f32_16x16x32_bf16(             \
                    qfrag[ks], bf, sacc[j], 0, 0, 0);                          \
            }                                                                  \
        _Pragma("unroll")                                                      \
        for (int r = 0; r < 4; r++) {                                          \
            const float p0 = exp2f(sacc[0][r]);                                \
            const float p1 = exp2f(sacc[1][r]);                                \
            const float p2 = exp2f(sacc[2][r]);                                \
            const float p3 = exp2f(sacc[3][r]);                                \
            lsum[r] += (p0 + p1) + (p2 + p3);                                  \
            uint2 pk = {pack_bf2(p0, p1), pack_bf2(p2, p3)};                   \
            *(uint2*)&Ps[(wave * 16 + quad * 4 + r) * 72 + l16 * 4] = pk;      \
        }                                                                      \
        _Pragma("unroll")                                                      \
        for (int ks = 0; ks < 2; ks++) {                                       \
            const bf16x8 pf = *(const bf16x8*)&Ps[(wave * 16 + l16) * 72 +     \
                ks * 32 + quad * 8];                                           \
            _Pragma("unroll")                                                  \
            for (int j = 0; j < 4; j++) {                                      \
                const bf16x8 vf = *(const bf16x8*)&smem[9216 + (CO) +          \
                    (j * 16 + l16) * 72 + ks * 32 + quad * 8];                 \
                oacc[j] = __builtin_amdgcn_mfma_f32_16x16x32_bf16(             \
                    pf, vf, oacc[j], 0, 0, 0);                                 \
            }                                                                  \
        }                                                                      \
        if (PF) {                                                              \
            *(uint4*)&smem[(NO) + srow * 72 + scg]            = kreg[0];       \
            *(uint4*)&smem[(NO) + srow * 72 + scg + 8]        = kreg[1];       \
            *(uint4*)&smem[9216 + (NO) + srow * 72 + scg]     = vreg[0];       \
            *(uint4*)&smem[9216 + (NO) + srow * 72 + scg + 8] = vreg[1];       \
        }                                                                      \
    }

    for (int it2 = 0; it2 < 16; ++it2) {
        ATTN_STEP(0, 4608, 1)                    // compute buf0, fill buf1
        ATTN_STEP(4608, 0, (it2 < 15))           // compute buf1, fill buf0
    }
#undef ATTN_STEP

#pragma unroll
    for (int r = 0; r < 4; r++) {
#pragma unroll
        for (int off = 1; off < 16; off <<= 1)
            lsum[r] += __shfl_xor(lsum[r], off, 64);
        lsum[r] = 1.f / lsum[r];
    }

    // epilogue: bf16 via LDS (wave-local rows of Ps), b128 swizzled stores
    __syncthreads();
#pragma unroll
    for (int j = 0; j < 4; j++)
#pragma unroll
        for (int r = 0; r < 4; r++)
            Ps[(wave * 16 + quad * 4 + r) * 72 + j * 16 + l16] =
                f2bf(oacc[j][r] * lsum[r]);

    const int b = bh / H_, h = bh % H_;
    const int row = t >> 2;
    const int c0  = (t & 3) * 16;
    const int qrow = qtile * 64 + row;
    const int key  = qrow & 7;
    const uint4 v0 = *(const uint4*)&Ps[row * 72 + c0];
    const uint4 v1 = *(const uint4*)&Ps[row * 72 + c0 + 8];
    const int g8 = c0 >> 3;
    unsigned short* dst = Ao + (long)(b * S_ + qrow) * D_ + h * DK_;
    *(uint4*)(dst + ((g8 ^ key) * 8))       = v0;
    *(uint4*)(dst + (((g8 + 1) ^ key) * 8)) = v1;
}

// ---------------------------------------------------------------------------
// Output projection: Ao_sw bf16 @ Wo_sw -> fp32 d_out + bias. Tile 64x64,
// grid (64,12)=768 = 3/CU; launch_bounds(256,4) so all blocks resident.
// 4 waves 2x2 (wave 32x32), both operands async. Single-pass LDS epilogue.
// ---------------------------------------------------------------------------
__global__ __launch_bounds__(256, 4) void gemm_out(
    const unsigned short* __restrict__ A, const unsigned short* __restrict__ Wsw,
    const float* __restrict__ bias, float* __restrict__ Out)
{
    __shared__ __align__(16) unsigned short smem[8704];
    unsigned short* As = smem;           // [64][64] swizzled
    unsigned short* Bs = smem + 4096;    // [64][64] swizzled

    const int t    = threadIdx.x;
    const int wave = t >> 6;
    const int lane = t & 63;
    const int l16  = lane & 15;
    const int quad = lane >> 4;
    const int wm   = wave >> 1, wn = wave & 1;
    const int m0   = blockIdx.x * 64;
    const int n0   = blockIdx.y * 64;

    f32x4 acc[2][2];
#pragma unroll
    for (int s = 0; s < 2; s++)
#pragma unroll
        for (int j = 0; j < 2; j++) acc[s][j] = (f32x4){0.f, 0.f, 0.f, 0.f};

    const int lrow = lane >> 3;
    const int lcg  = lane & 7;

    for (int k0 = 0; k0 < D_; k0 += 64) {
        __syncthreads();
#pragma unroll
        for (int i = 0; i < 2; i++) {
            const int chunk = wave * 2 + i;
            async_cp16(A + (long)(m0 + chunk * 8 + lrow) * D_ + k0 + lcg * 8,
                       As + chunk * 512);
        }
#pragma unroll
        for (int i = 0; i < 2; i++) {
            const int chunk = wave * 2 + i;
            async_cp16(Wsw + (long)(n0 + chunk * 8 + lrow) * D_ + k0 + lcg * 8,
                       Bs + chunk * 512);
        }
        __syncthreads();
#pragma unroll
        for (int ks = 0; ks < 2; ks++) {
            const int cg = ks * 4 + quad;
            bf16x8 af[2], bf[2];
#pragma unroll
            for (int s = 0; s < 2; s++) {
                const int r = wm * 32 + s * 16 + l16;
                af[s] = *(const bf16x8*)&As[r * 64 + ((cg ^ (r & 7)) * 8)];
            }
#pragma unroll
            for (int j = 0; j < 2; j++) {
                const int r = wn * 32 + j * 16 + l16;
                bf[j] = *(const bf16x8*)&Bs[r * 64 + ((cg ^ (r & 7)) * 8)];
            }
#pragma unroll
            for (int s = 0; s < 2; s++)
#pragma unroll
                for (int j = 0; j < 2; j++)
                    acc[s][j] = __builtin_amdgcn_mfma_f32_16x16x32_bf16(af[s], bf[j], acc[s][j], 0, 0, 0);
        }
    }

    float bv[2];
#pragma unroll
    for (int j = 0; j < 2; j++) bv[j] = bias[n0 + wn * 32 + j * 16 + l16];

    __syncthreads();                     // done with As/Bs before reuse
    float* fl = (float*)smem;            // [64][67] = 17152 B <= 17408
#pragma unroll
    for (int s = 0; s < 2; s++)
#pragma unroll
        for (int j = 0; j < 2; j++)
#pragma unroll
            for (int r = 0; r < 4; r++)
                fl[(wm * 32 + s * 16 + quad * 4 + r) * 67 + wn * 32 + j * 16 + l16] =
                    acc[s][j][r] + bv[j];
    __syncthreads();
    const int row = t >> 2, c0 = (t & 3) * 16;
#pragma unroll
    for (int i = 0; i < 4; i++) {
        const float4 v = *(const float4*)&fl[row * 67 + c0 + i * 4];
        *(float4*)(Out + (long)(m0 + row) * D_ + n0 + c0 + i * 4) = v;
    }
}

extern "C" void kernel_launch(void* const* d_in, const int* in_sizes, int n_in,
                              void* d_out, int out_size, void* d_ws, size_t ws_size,
                              hipStream_t stream) {
    const float* k_in = (const float*)d_in[0];
    const float* q_in = (const float*)d_in[1];
    const float* v_in = (const float*)d_in[2];
    // d_in[3] = mask: no-op per reference
    const float* wq = (const float*)d_in[4];
    const float* bq = (const float*)d_in[5];
    const float* wk = (const float*)d_in[6];
    const float* bk = (const float*)d_in[7];
    const float* wv = (const float*)d_in[8];
    const float* bv = (const float*)d_in[9];
    const float* wo = (const float*)d_in[10];
    const float* bo = (const float*)d_in[11];

    unsigned short* ws = (unsigned short*)d_ws;
    unsigned short* Wsw = ws;                          // 4*NW bf16 swizzled
    unsigned short* Qb  = Wsw + 4ll * NW_;             // NX bf16
    unsigned short* Kb  = Qb + (long)NX_;
    unsigned short* Vt  = Kb + (long)NX_;
    unsigned short* Xsw = Vt + (long)NX_;              // 3*NX (dead after qkv)
    unsigned short* Ao  = Xsw;                         // aliases Xsw

    CvtArgs ca;
    ca.s[0] = q_in; ca.s[1] = k_in; ca.s[2] = v_in;
    ca.s[3] = wq;   ca.s[4] = wk;   ca.s[5] = wv;  ca.s[6] = wo;
    cvt_all<<<dim3(5760), 256, 0, stream>>>(ca, Xsw, Wsw);

    QkvArgs qa;
    qa.bias[0] = bq; qa.bias[1] = bk; qa.bias[2] = bv;
    qa.out[0] = Qb;  qa.out[1] = Kb;  qa.out[2] = Vt;
    gemm_qkv<<<dim3(32, 18), 256, 0, stream>>>(qa, Xsw, Wsw);

    attn_kernel<<<dim3(S_ / 64, B_ * H_), 256, 0, stream>>>(Qb, Kb, Vt, Ao);

    gemm_out<<<dim3(64, 12), 256, 0, stream>>>(Ao, Wsw + 3ll * NW_, bo, (float*)d_out);
}

// Round 10
// 214.463 us; speedup vs baseline: 1.0431x; 1.0008x over previous
//
#include <hip/hip_runtime.h>
#include <hip/hip_bf16.h>

// MHA: B=2 S=2048 D=768 H=12 DK=64. fp32 in/out; bf16 MFMA internally.
#define B_  2
#define S_  2048
#define D_  768
#define H_  12
#define DK_ 64
#define NX_ (B_*S_*D_)      // 3145728 activation elements
#define NW_ (D_*D_)         // 589824 weight elements
#define CSC 0.18033688011112042f   // 0.125 * log2(e), baked into wq/bq

typedef __attribute__((ext_vector_type(8))) short  bf16x8;
typedef __attribute__((ext_vector_type(4))) float  f32x4;

__device__ __forceinline__ unsigned short f2bf(float f) {
    unsigned int u = __float_as_uint(f);
    u += 0x7fffu + ((u >> 16) & 1u);   // RNE
    return (unsigned short)(u >> 16);
}

// pack two fp32 -> two bf16 (+0x8000 then hi16) in 3 VALU ops
__device__ __forceinline__ unsigned pack_bf2(float a, float b) {
    const unsigned ua = __float_as_uint(a) + 0x8000u;
    const unsigned ub = __float_as_uint(b) + 0x8000u;
    return __builtin_amdgcn_perm(ub, ua, 0x07060302u);
}

__device__ __forceinline__ void async_cp16(const unsigned short* g,
                                           const unsigned short* lds_uniform_base) {
    __builtin_amdgcn_global_load_lds(
        (const __attribute__((address_space(1))) unsigned int*)(uintptr_t)g,
        (__attribute__((address_space(3))) unsigned int*)(unsigned int)(uintptr_t)lds_uniform_base,
        16, 0, 0);
}

// ---------------------------------------------------------------------------
// Fused fp32->bf16 cvt, xor-swizzled per 64-el k-block (group g8 -> g8^(n&7)).
// 16 elements/thread. 1D grid: 3*768 activation blocks + 4*144 weight blocks.
// ---------------------------------------------------------------------------
struct CvtArgs { const float* s[7]; };

__global__ __launch_bounds__(256) void cvt_all(CvtArgs a,
                                               unsigned short* __restrict__ Xsw,
                                               unsigned short* __restrict__ Wsw) {
    const int bx = blockIdx.x;
    int y, inner;
    if (bx < 2304) { y = bx / 768;             inner = bx % 768; }
    else           { y = 3 + (bx - 2304) / 144; inner = (bx - 2304) % 144; }
    const int idx = inner * 256 + threadIdx.x;
    const int n  = idx / 48;
    const int g2 = idx % 48;                  // 16-el group in row
    const float* src = a.s[y] + (long)n * D_ + g2 * 16;
    const float zs = (y == 3) ? CSC : 1.0f;
    unsigned short o[16];
#pragma unroll
    for (int i = 0; i < 4; i++) {
        const float4 f = *(const float4*)(src + i * 4);
        o[i*4+0] = f2bf(f.x*zs); o[i*4+1] = f2bf(f.y*zs);
        o[i*4+2] = f2bf(f.z*zs); o[i*4+3] = f2bf(f.w*zs);
    }
    unsigned short* dst = (y >= 3) ? (Wsw + (long)(y - 3) * NW_ + (long)n * D_)
                                   : (Xsw + (long)y * NX_ + (long)n * D_);
    const int key = n & 7;
#pragma unroll
    for (int h = 0; h < 2; h++) {
        const int g8 = g2 * 2 + h;
        const int kdst = (g8 >> 3) * 64 + (((g8 & 7) ^ key) * 8);
        *(uint4*)(dst + kdst) = *(const uint4*)&o[h * 8];
    }
}

// ---------------------------------------------------------------------------
// Fused QKV projection. grid(32, 18): y -> zz = y/6, nb = y%6. Tile 128x128,
// BK=64, 4 waves 2x2. Both operands async-staged from swizzled bf16 global.
// launch_bounds(256,3): all 576 blocks resident (no tail round).
// Outputs: Q/K [bh][s][dk]; V transposed+pi-permuted [bh][dk][s'].
// ---------------------------------------------------------------------------
struct QkvArgs { const float* bias[3]; unsigned short* out[3]; };

__global__ __launch_bounds__(256, 3) void gemm_qkv(QkvArgs args,
                                                   const unsigned short* __restrict__ Xsw,
                                                   const unsigned short* __restrict__ Wsw) {
    __shared__ __align__(16) unsigned short smem[17408];
    unsigned short* As = smem;           // [128][64] swizzled
    unsigned short* Bs = smem + 8192;    // [128][64] swizzled

    const int t    = threadIdx.x;
    const int wave = t >> 6;
    const int lane = t & 63;
    const int l16  = lane & 15;
    const int quad = lane >> 4;
    const int wm   = wave >> 1, wn = wave & 1;
    const int m0   = blockIdx.x * 128;
    const int zz   = blockIdx.y / 6;
    const int nb   = blockIdx.y % 6;
    const int n0   = nb * 128;

    const unsigned short* Ap = Xsw + (long)zz * NX_;
    const unsigned short* Wp = Wsw + (long)zz * NW_;

    f32x4 acc[4][4];
#pragma unroll
    for (int s = 0; s < 4; s++)
#pragma unroll
        for (int j = 0; j < 4; j++) acc[s][j] = (f32x4){0.f, 0.f, 0.f, 0.f};

    const int lrow = lane >> 3;
    const int lcg  = lane & 7;

    for (int k0 = 0; k0 < D_; k0 += 64) {
        __syncthreads();
#pragma unroll
        for (int i = 0; i < 4; i++) {
            const int chunk = wave * 4 + i;
            async_cp16(Ap + (long)(m0 + chunk * 8 + lrow) * D_ + k0 + lcg * 8,
                       As + chunk * 512);
        }
#pragma unroll
        for (int i = 0; i < 4; i++) {
            const int chunk = wave * 4 + i;
            async_cp16(Wp + (long)(n0 + chunk * 8 + lrow) * D_ + k0 + lcg * 8,
                       Bs + chunk * 512);
        }
        __syncthreads();
#pragma unroll
        for (int ks = 0; ks < 2; ks++) {
            const int cg = ks * 4 + quad;
            bf16x8 af[4], bf[4];
#pragma unroll
            for (int s = 0; s < 4; s++) {
                const int r = wm * 64 + s * 16 + l16;
                af[s] = *(const bf16x8*)&As[r * 64 + ((cg ^ (r & 7)) * 8)];
            }
#pragma unroll
            for (int j = 0; j < 4; j++) {
                const int r = wn * 64 + j * 16 + l16;
                bf[j] = *(const bf16x8*)&Bs[r * 64 + ((cg ^ (r & 7)) * 8)];
            }
#pragma unroll
            for (int s = 0; s < 4; s++)
#pragma unroll
                for (int j = 0; j < 4; j++)
                    acc[s][j] = __builtin_amdgcn_mfma_f32_16x16x32_bf16(af[s], bf[j], acc[s][j], 0, 0, 0);
        }
    }
    __syncthreads();

    const int b     = m0 >> 11;
    const int sbase = m0 & (S_ - 1);
    const float zs  = (zz == 0) ? CSC : 1.0f;
    float bv[4];
#pragma unroll
    for (int j = 0; j < 4; j++) bv[j] = args.bias[zz][n0 + wn * 64 + j * 16 + l16] * zs;

    if (zz < 2) {
        unsigned short* Ls = smem;       // [128][136]
#pragma unroll
        for (int s = 0; s < 4; s++)
#pragma unroll
            for (int j = 0; j < 4; j++)
#pragma unroll
                for (int r = 0; r < 4; r++)
                    Ls[(wm * 64 + s * 16 + quad * 4 + r) * 136 + wn * 64 + j * 16 + l16] =
                        f2bf(acc[s][j][r] + bv[j]);
        __syncthreads();
        const int row  = t >> 1;
        const int half = t & 1;
        unsigned short* Op = args.out[zz];
#pragma unroll
        for (int i = 0; i < 8; i++) {
            const int col  = half * 64 + i * 8;
            const int head = nb * 2 + half;
            const uint4 v = *(const uint4*)&Ls[row * 136 + col];
            *(uint4*)(Op + ((long)(b * H_ + head) * S_ + sbase + row) * DK_ + (col & 63)) = v;
        }
    } else {
        unsigned short* Ls = smem;       // [2][64][136]
#pragma unroll
        for (int s = 0; s < 4; s++)
#pragma unroll
            for (int j = 0; j < 4; j++)
#pragma unroll
                for (int r = 0; r < 4; r++) {
                    const int dk  = j * 16 + l16;
                    const int pos = wm * 64 + (quad * 4 + r) * 4 + s;   // pi-permute
                    Ls[wn * 8704 + dk * 136 + pos] = f2bf(acc[s][j][r] + bv[j]);
                }
        __syncthreads();
        const int rowIdx = t >> 1;
        const int hh = rowIdx >> 6, dk = rowIdx & 63;
        const int half = t & 1;
        unsigned short* Op = args.out[2];
#pragma unroll
        for (int i = 0; i < 8; i++) {
            const int col = half * 64 + i * 8;
            const uint4 v = *(const uint4*)&Ls[hh * 8704 + dk * 136 + col];
            const int head = nb * 2 + hh;
            *(uint4*)(Op + ((long)(b * H_ + head) * DK_ + dk) * S_ + sbase + col) = v;
        }
    }
}

// ---------------------------------------------------------------------------
// Flash attention: R7 structure (proven 60.6 us). 64-row q-tiles, 4 waves,
// grid (32,24)=768 = 3/CU. No-max softmax (scale baked into Q), pi-permuted
// packed P-stores, piV, double-buffered K/V LDS + register prefetch with
// ROLLING pointers (no per-iter 64-bit addr recompute). One barrier per tile.
// ---------------------------------------------------------------------------
__global__ __launch_bounds__(256, 3) void attn_kernel(
    const unsigned short* __restrict__ Q, const unsigned short* __restrict__ K,
    const unsigned short* __restrict__ Vt, unsigned short* __restrict__ Ao)
{
    const int t    = threadIdx.x;
    const int wave = t >> 6;
    const int lane = t & 63;
    const int l16  = lane & 15;
    const int quad = lane >> 4;
    const int qtile = blockIdx.x;       // 32 tiles of 64 rows
    const int bh    = blockIdx.y;       // 24

    const unsigned short* Qp = Q  + (long)bh * S_ * DK_;
    const unsigned short* Kp = K  + (long)bh * S_ * DK_;
    const unsigned short* Vp = Vt + (long)bh * DK_ * S_;

    __shared__ __align__(16) unsigned short smem[23040];   // 45 KB
    // Ks0@0  Ks1@4608  Vs0@9216  Vs1@13824  Ps@18432  (each [64][72])
    unsigned short* Ps = smem + 18432;

    bf16x8 qfrag[2];
    {
        const long qoff = (long)(qtile * 64 + wave * 16 + l16) * DK_ + quad * 8;
        qfrag[0] = *(const bf16x8*)(Qp + qoff);
        qfrag[1] = *(const bf16x8*)(Qp + qoff + 32);
    }

    const int srow = t >> 2;            // 0..63
    const int scg  = (t & 3) * 16;
    uint4 kreg[2], vreg[2];
    // rolling source pointers
    const unsigned short* gk = Kp + (long)srow * DK_ + scg;
    const unsigned short* gv = Vp + (long)srow * S_ + scg;
    // tile 0 -> buffer 0
    kreg[0] = *(const uint4*)gk;  kreg[1] = *(const uint4*)(gk + 8);
    vreg[0] = *(const uint4*)gv;  vreg[1] = *(const uint4*)(gv + 8);
    gk += 64 * DK_;  gv += 64;
    *(uint4*)&smem[srow * 72 + scg]            = kreg[0];
    *(uint4*)&smem[srow * 72 + scg + 8]        = kreg[1];
    *(uint4*)&smem[9216 + srow * 72 + scg]     = vreg[0];
    *(uint4*)&smem[9216 + srow * 72 + scg + 8] = vreg[1];

    f32x4 oacc[4];
#pragma unroll
    for (int j = 0; j < 4; j++) oacc[j] = (f32x4){0.f, 0.f, 0.f, 0.f};
    float lsum[4] = {0.f, 0.f, 0.f, 0.f};

    for (int it = 0; it < 32; ++it) {
        const int co = (it & 1) * 4608;          // current buffer offset
        const int no = ((it & 1) ^ 1) * 4608;    // next buffer offset
        __syncthreads();                 // prev-iter commits visible
        const unsigned short* Ks = smem + co;
        const unsigned short* Vs = smem + 9216 + co;

        if (it < 31) {                   // prefetch next tile into registers
            kreg[0] = *(const uint4*)gk;  kreg[1] = *(const uint4*)(gk + 8);
            vreg[0] = *(const uint4*)gv;  vreg[1] = *(const uint4*)(gv + 8);
            gk += 64 * DK_;  gv += 64;
        }

        // S = Q K^T
        f32x4 sacc[4];
#pragma unroll
        for (int j = 0; j < 4; j++) sacc[j] = (f32x4){0.f, 0.f, 0.f, 0.f};
#pragma unroll
        for (int ks = 0; ks < 2; ks++)
#pragma unroll
            for (int j = 0; j < 4; j++) {
                const bf16x8 bf = *(const bf16x8*)&Ks[(j * 16 + l16) * 72 + ks * 32 + quad * 8];
                sacc[j] = __builtin_amdgcn_mfma_f32_16x16x32_bf16(qfrag[ks], bf, sacc[j], 0, 0, 0);
            }

        // p = exp2(s); packed b64 P-stores, pi-permuted columns
#pragma unroll
        for (int r = 0; r < 4; r++) {
            const float p0 = exp2f(sacc[0][r]);
            const float p1 = exp2f(sacc[1][r]);
            const float p2 = exp2f(sacc[2][r]);
            const float p3 = exp2f(sacc[3][r]);
            lsum[r] += (p0 + p1) + (p2 + p3);
            uint2 pk = {pack_bf2(p0, p1), pack_bf2(p2, p3)};
            *(uint2*)&Ps[(wave * 16 + quad * 4 + r) * 72 + l16 * 4] = pk;
        }

        // O += P V (wave-local P rows: lgkmcnt ordering only, no barrier)
#pragma unroll
        for (int ks = 0; ks < 2; ks++) {
            const bf16x8 pf = *(const bf16x8*)&Ps[(wave * 16 + l16) * 72 + ks * 32 + quad * 8];
#pragma unroll
            for (int j = 0; j < 4; j++) {
                const bf16x8 vf = *(const bf16x8*)&Vs[(j * 16 + l16) * 72 + ks * 32 + quad * 8];
                oacc[j] = __builtin_amdgcn_mfma_f32_16x16x32_bf16(pf, vf, oacc[j], 0, 0, 0);
            }
        }

        if (it < 31) {                   // commit prefetch to other buffer
            *(uint4*)&smem[no + srow * 72 + scg]            = kreg[0];
            *(uint4*)&smem[no + srow * 72 + scg + 8]        = kreg[1];
            *(uint4*)&smem[9216 + no + srow * 72 + scg]     = vreg[0];
            *(uint4*)&smem[9216 + no + srow * 72 + scg + 8] = vreg[1];
        }
    }

#pragma unroll
    for (int r = 0; r < 4; r++) {
#pragma unroll
        for (int off = 1; off < 16; off <<= 1)
            lsum[r] += __shfl_xor(lsum[r], off, 64);
        lsum[r] = 1.f / lsum[r];
    }

    // epilogue: bf16 via LDS (wave-local rows of Ps), b128 swizzled stores
    __syncthreads();
#pragma unroll
    for (int j = 0; j < 4; j++)
#pragma unroll
        for (int r = 0; r < 4; r++)
            Ps[(wave * 16 + quad * 4 + r) * 72 + j * 16 + l16] =
                f2bf(oacc[j][r] * lsum[r]);

    const int b = bh / H_, h = bh % H_;
    const int row = t >> 2;             // wave-local rows: no barrier needed
    const int c0  = (t & 3) * 16;
    const int qrow = qtile * 64 + row;
    const int key  = qrow & 7;
    const uint4 v0 = *(const uint4*)&Ps[row * 72 + c0];
    const uint4 v1 = *(const uint4*)&Ps[row * 72 + c0 + 8];
    const int g8 = c0 >> 3;
    unsigned short* dst = Ao + (long)(b * S_ + qrow) * D_ + h * DK_;
    *(uint4*)(dst + ((g8 ^ key) * 8))       = v0;
    *(uint4*)(dst + (((g8 + 1) ^ key) * 8)) = v1;
}

// ---------------------------------------------------------------------------
// Output projection: Ao_sw bf16 @ Wo_sw -> fp32 d_out + bias. Tile 64x64,
// grid (64,12)=768 = 3/CU; launch_bounds(256,4) so all blocks resident.
// 4 waves 2x2 (wave 32x32), both operands async. Single-pass LDS epilogue.
// ---------------------------------------------------------------------------
__global__ __launch_bounds__(256, 4) void gemm_out(
    const unsigned short* __restrict__ A, const unsigned short* __restrict__ Wsw,
    const float* __restrict__ bias, float* __restrict__ Out)
{
    __shared__ __align__(16) unsigned short smem[8704];
    unsigned short* As = smem;           // [64][64] swizzled
    unsigned short* Bs = smem + 4096;    // [64][64] swizzled

    const int t    = threadIdx.x;
    const int wave = t >> 6;
    const int lane = t & 63;
    const int l16  = lane & 15;
    const int quad = lane >> 4;
    const int wm   = wave >> 1, wn = wave & 1;
    const int m0   = blockIdx.x * 64;
    const int n0   = blockIdx.y * 64;

    f32x4 acc[2][2];
#pragma unroll
    for (int s = 0; s < 2; s++)
#pragma unroll
        for (int j = 0; j < 2; j++) acc[s][j] = (f32x4){0.f, 0.f, 0.f, 0.f};

    const int lrow = lane >> 3;
    const int lcg  = lane & 7;

    for (int k0 = 0; k0 < D_; k0 += 64) {
        __syncthreads();
#pragma unroll
        for (int i = 0; i < 2; i++) {
            const int chunk = wave * 2 + i;
            async_cp16(A + (long)(m0 + chunk * 8 + lrow) * D_ + k0 + lcg * 8,
                       As + chunk * 512);
        }
#pragma unroll
        for (int i = 0; i < 2; i++) {
            const int chunk = wave * 2 + i;
            async_cp16(Wsw + (long)(n0 + chunk * 8 + lrow) * D_ + k0 + lcg * 8,
                       Bs + chunk * 512);
        }
        __syncthreads();
#pragma unroll
        for (int ks = 0; ks < 2; ks++) {
            const int cg = ks * 4 + quad;
            bf16x8 af[2], bf[2];
#pragma unroll
            for (int s = 0; s < 2; s++) {
                const int r = wm * 32 + s * 16 + l16;
                af[s] = *(const bf16x8*)&As[r * 64 + ((cg ^ (r & 7)) * 8)];
            }
#pragma unroll
            for (int j = 0; j < 2; j++) {
                const int r = wn * 32 + j * 16 + l16;
                bf[j] = *(const bf16x8*)&Bs[r * 64 + ((cg ^ (r & 7)) * 8)];
            }
#pragma unroll
            for (int s = 0; s < 2; s++)
#pragma unroll
                for (int j = 0; j < 2; j++)
                    acc[s][j] = __builtin_amdgcn_mfma_f32_16x16x32_bf16(af[s], bf[j], acc[s][j], 0, 0, 0);
        }
    }

    float bv[2];
#pragma unroll
    for (int j = 0; j < 2; j++) bv[j] = bias[n0 + wn * 32 + j * 16 + l16];

    __syncthreads();                     // done with As/Bs before reuse
    float* fl = (float*)smem;            // [64][67]
#pragma unroll
    for (int s = 0; s < 2; s++)
#pragma unroll
        for (int j = 0; j < 2; j++)
#pragma unroll
            for (int r = 0; r < 4; r++)
                fl[(wm * 32 + s * 16 + quad * 4 + r) * 67 + wn * 32 + j * 16 + l16] =
                    acc[s][j][r] + bv[j];
    __syncthreads();
    const int row = t >> 2, c0 = (t & 3) * 16;
#pragma unroll
    for (int i = 0; i < 4; i++) {
        const float4 v = *(const float4*)&fl[row * 67 + c0 + i * 4];
        *(float4*)(Out + (long)(m0 + row) * D_ + n0 + c0 + i * 4) = v;
    }
}

extern "C" void kernel_launch(void* const* d_in, const int* in_sizes, int n_in,
                              void* d_out, int out_size, void* d_ws, size_t ws_size,
                              hipStream_t stream) {
    const float* k_in = (const float*)d_in[0];
    const float* q_in = (const float*)d_in[1];
    const float* v_in = (const float*)d_in[2];
    // d_in[3] = mask: no-op per reference
    const float* wq = (const float*)d_in[4];
    const float* bq = (const float*)d_in[5];
    const float* wk = (const float*)d_in[6];
    const float* bk = (const float*)d_in[7];
    const float* wv = (const float*)d_in[8];
    const float* bv = (const float*)d_in[9];
    const float* wo = (const float*)d_in[10];
    const float* bo = (const float*)d_in[11];

    unsigned short* ws = (unsigned short*)d_ws;
    unsigned short* Wsw = ws;                          // 4*NW bf16 swizzled
    unsigned short* Qb  = Wsw + 4ll * NW_;             // NX bf16
    unsigned short* Kb  = Qb + (long)NX_;
    unsigned short* Vt  = Kb + (long)NX_;
    unsigned short* Xsw = Vt + (long)NX_;              // 3*NX (dead after qkv)
    unsigned short* Ao  = Xsw;                         // aliases Xsw

    CvtArgs ca;
    ca.s[0] = q_in; ca.s[1] = k_in; ca.s[2] = v_in;
    ca.s[3] = wq;   ca.s[4] = wk;   ca.s[5] = wv;  ca.s[6] = wo;
    cvt_all<<<dim3(2880), 256, 0, stream>>>(ca, Xsw, Wsw);

    QkvArgs qa;
    qa.bias[0] = bq; qa.bias[1] = bk; qa.bias[2] = bv;
    qa.out[0] = Qb;  qa.out[1] = Kb;  qa.out[2] = Vt;
    gemm_qkv<<<dim3(32, 18), 256, 0, stream>>>(qa, Xsw, Wsw);

    attn_kernel<<<dim3(S_ / 64, B_ * H_), 256, 0, stream>>>(Qb, Kb, Vt, Ao);

    gemm_out<<<dim3(64, 12), 256, 0, stream>>>(Ao, Wsw + 3ll * NW_, bo, (float*)d_out);
}